// Round 1
// 912.456 us; speedup vs baseline: 1.0551x; 1.0551x over previous
//
#include <hip/hip_runtime.h>
#include <stdint.h>
#include <stddef.h>

// Problem constants
#define N_Q 256        // queries
#define M_D 50000      // dataset rows
#define K_D 3072       // feature dim
#define MT 64          // dataset rows per workgroup in scores GEMM
#define BK 64          // K-slice per iteration (2 MFMA K-steps)
#define NKT (K_D / BK) // 48
#define CAND_CAP 128   // max candidates per row
#define WINDOW 9.0f    // raw-score candidate window (36 logits; bf16 err bound ~0.6)
#define SPLIT 8        // scan blocks per score row

typedef short bf16x8 __attribute__((ext_vector_type(8)));   // 8 bf16 = 4 VGPRs
typedef float f32x4 __attribute__((ext_vector_type(4)));

// fp32 -> bf16 round-to-nearest-even
static __device__ __forceinline__ unsigned short f2bf(float f) {
    unsigned int u = __float_as_uint(f);
    u += 0x7fffu + ((u >> 16) & 1u);
    return (unsigned short)(u >> 16);
}

// async global->LDS, 16B per lane; LDS dest = wave-uniform base + lane*16
static __device__ __forceinline__ void load_lds16(const short* g, short* l) {
    __builtin_amdgcn_global_load_lds(
        (const __attribute__((address_space(1))) void*)g,
        (__attribute__((address_space(3))) void*)l, 16, 0, 0);
}

// ---------------------------------------------------------------------------
// K0: convert x [256x3072] fp32 -> bf16
// ---------------------------------------------------------------------------
__global__ __launch_bounds__(256) void cvt_x_kernel(const float* __restrict__ x,
                                                    short* __restrict__ xb) {
    int i = (blockIdx.x * 256 + threadIdx.x) * 4;   // grid covers exactly 786432
    float4 f = *(const float4*)(x + i);
    ushort4 o;
    o.x = f2bf(f.x); o.y = f2bf(f.y); o.z = f2bf(f.z); o.w = f2bf(f.w);
    *(ushort4*)(xb + i) = o;
}

// ---------------------------------------------------------------------------
// K1: scores[n][m] = sum_k xb[n][k] * bf16(dataset[m][k])   (raw dot, no temp)
// One WG computes 256x64 of scores. 4 waves, wave w owns rows [w*64, w*64+64).
// LDS layout (both tiles): 16B chunks, position-in-row = chunk ^ (row & 7)
//   -> ds_read_b128 frag reads are 2-way (free) instead of 8-way conflicted.
// A (xb, bf16-ready) staged via global_load_lds with pre-swizzled SOURCE
// (linear LDS dest, rule #21). B (fp32->bf16) reg-staged one K-tile ahead.
// ---------------------------------------------------------------------------
__global__ __launch_bounds__(256) void gemm_scores(const short* __restrict__ xb,
                                                   const float* __restrict__ dset,
                                                   float* __restrict__ scores) {
    __shared__ __align__(16) short sA[N_Q * BK];   // 32 KB, swizzled chunks
    __shared__ __align__(16) short sB[MT * BK];    // 8 KB, swizzled chunks

    const int tid = threadIdx.x;
    const int w = tid >> 6;        // wave 0..3
    const int l = tid & 63;        // lane
    const int m0 = blockIdx.x * MT;

    f32x4 acc[4][4];
#pragma unroll
    for (int i = 0; i < 4; ++i)
#pragma unroll
        for (int j = 0; j < 4; ++j)
            acc[i][j] = (f32x4){0.f, 0.f, 0.f, 0.f};

    // ---- A staging geometry: wave w, step j stages rows (w + j*4)*8 .. +8.
    // lane: row-in-group ar = l>>3, writes LDS chunk (linear) = base + l,
    // i.e. position l&7 of its row; source chunk = (l&7) ^ ar  (involution).
    const int ar = l >> 3;
    const int aq = (l & 7) ^ ar;
    const short* abase = xb + (size_t)(w * 8 + ar) * K_D + aq * 8;
    short* adst = &sA[w * 512];    // group stride 512 shorts; j adds 4 groups

    // ---- B staging geometry: thread handles chunk c=tid (rows 0..31) and
    // c=tid+256 (rows 32..63): row = c>>3, chunk q = c&7, 8 floats each.
    const int r1 = tid >> 3;            // 0..31
    const int q1 = tid & 7;
    const int r2 = r1 + 32;
    const bool v1 = (m0 + r1) < M_D;
    const bool v2 = (m0 + r2) < M_D;
    const float* b1 = dset + (size_t)(m0 + r1) * K_D + q1 * 8;
    const float* b2 = dset + (size_t)(m0 + r2) * K_D + q1 * 8;
    short* w1p = &sB[(size_t)((r1 << 3) + (q1 ^ (r1 & 7))) << 3];
    short* w2p = &sB[(size_t)((r2 << 3) + (q1 ^ (r2 & 7))) << 3];

    // prefetch B slice for kt=0 (invalid rows stay zero forever)
    float4 f0a = {0,0,0,0}, f0b = {0,0,0,0}, f1a = {0,0,0,0}, f1b = {0,0,0,0};
    if (v1) { f0a = *(const float4*)b1; f0b = *(const float4*)(b1 + 4); }
    if (v2) { f1a = *(const float4*)b2; f1b = *(const float4*)(b2 + 4); }

    const int rA = l & 15;         // fragment row-within-16
    const int r7 = l & 7;
    const int kq = l >> 4;         // lane's 16B chunk within 32-K half

    for (int kt = 0; kt < NKT; ++kt) {
        __syncthreads();   // previous tile's ds_reads complete

        // --- A: 8 gload_lds per wave, 8 rows x 128B each, swizzled source
#pragma unroll
        for (int j = 0; j < 8; ++j)
            load_lds16(abase + (size_t)j * (32 * K_D) + kt * BK, adst + j * 2048);

        // --- B: convert prefetched regs, swizzled ds_write_b128
        {
            bf16x8 p;
            p[0] = (short)f2bf(f0a.x); p[1] = (short)f2bf(f0a.y);
            p[2] = (short)f2bf(f0a.z); p[3] = (short)f2bf(f0a.w);
            p[4] = (short)f2bf(f0b.x); p[5] = (short)f2bf(f0b.y);
            p[6] = (short)f2bf(f0b.z); p[7] = (short)f2bf(f0b.w);
            *(bf16x8*)w1p = p;
            p[0] = (short)f2bf(f1a.x); p[1] = (short)f2bf(f1a.y);
            p[2] = (short)f2bf(f1a.z); p[3] = (short)f2bf(f1a.w);
            p[4] = (short)f2bf(f1b.x); p[5] = (short)f2bf(f1b.y);
            p[6] = (short)f2bf(f1b.z); p[7] = (short)f2bf(f1b.w);
            *(bf16x8*)w2p = p;
        }
        __syncthreads();   // compiler drains vmcnt (gload_lds) + lgkm here

        // --- prefetch next B slice; latency hides under ds_read+MFMA below
        if (kt + 1 < NKT) {
            const int o = (kt + 1) * BK;
            if (v1) { f0a = *(const float4*)(b1 + o); f0b = *(const float4*)(b1 + o + 4); }
            if (v2) { f1a = *(const float4*)(b2 + o); f1b = *(const float4*)(b2 + o + 4); }
        }

        // --- fragments + MFMA (two 32-K halves; order matches old BK=32 loop)
#pragma unroll
        for (int h = 0; h < 2; ++h) {
            const int qs = (((h * 4 + kq) ^ r7) << 3);   // swizzled chunk offset (shorts)
            bf16x8 af[4], bfr[4];
#pragma unroll
            for (int ai = 0; ai < 4; ++ai)
                af[ai] = *(const bf16x8*)&sA[(size_t)(w * 64 + ai * 16 + rA) * 64 + qs];
#pragma unroll
            for (int bj = 0; bj < 4; ++bj)
                bfr[bj] = *(const bf16x8*)&sB[(size_t)(bj * 16 + rA) * 64 + qs];
#pragma unroll
            for (int ai = 0; ai < 4; ++ai)
#pragma unroll
                for (int bj = 0; bj < 4; ++bj)
                    acc[ai][bj] = __builtin_amdgcn_mfma_f32_16x16x32_bf16(
                        af[ai], bfr[bj], acc[ai][bj], 0, 0, 0);
        }
    }

    // epilogue: C/D layout col = l&15, row = (l>>4)*4 + r  [m89-verified]
    const int crow = (l >> 4) * 4;
    const int ccol = l & 15;
#pragma unroll
    for (int ai = 0; ai < 4; ++ai) {
#pragma unroll
        for (int bj = 0; bj < 4; ++bj) {
            int m = m0 + bj * 16 + ccol;
            if (m < M_D) {
#pragma unroll
                for (int r = 0; r < 4; ++r) {
                    int n = w * 64 + ai * 16 + crow + r;
                    scores[(size_t)n * M_D + m] = acc[ai][bj][r];
                }
            }
        }
    }
}

// ---------------------------------------------------------------------------
// K2a: per (row, segment): partial max over 1/8 of the row -> pmax[n][s]
//      (8 blocks/row -> 2048 blocks = 8/CU; hides HBM latency)
// ---------------------------------------------------------------------------
__global__ __launch_bounds__(256) void rowmax_kernel(const float* __restrict__ scores,
                                                     float* __restrict__ pmax,
                                                     int* __restrict__ ccnt) {
    const int n = blockIdx.x >> 3;
    const int s = blockIdx.x & 7;
    const int tid = threadIdx.x;
    const float4* row4 = (const float4*)(scores + (size_t)n * M_D);
    const int start = s * 1563;                 // 1563*8 = 12504 >= 12500
    int end = start + 1563; if (end > M_D / 4) end = M_D / 4;

    float mx = -3.0e38f;
    for (int i = start + tid; i < end; i += 256) {
        float4 v = row4[i];
        mx = fmaxf(mx, fmaxf(fmaxf(v.x, v.y), fmaxf(v.z, v.w)));
    }
#pragma unroll
    for (int off = 32; off > 0; off >>= 1) mx = fmaxf(mx, __shfl_down(mx, off));

    __shared__ float wred[4];
    if ((tid & 63) == 0) wred[tid >> 6] = mx;
    __syncthreads();
    if (tid == 0) {
        pmax[blockIdx.x] = fmaxf(fmaxf(wred[0], wred[1]), fmaxf(wred[2], wred[3]));
        if (s == 0) ccnt[n] = 0;                // zero counter for collect pass
    }
}

// ---------------------------------------------------------------------------
// K2b: per (row, segment): collect candidates with s >= rowmax - WINDOW
// ---------------------------------------------------------------------------
__global__ __launch_bounds__(256) void collect_kernel(const float* __restrict__ scores,
                                                      const float* __restrict__ pmax,
                                                      int* __restrict__ cidx,
                                                      int* __restrict__ ccnt) {
    const int n = blockIdx.x >> 3;
    const int s = blockIdx.x & 7;
    const int tid = threadIdx.x;

    float rm = -3.0e38f;
#pragma unroll
    for (int i = 0; i < 8; ++i) rm = fmaxf(rm, pmax[n * 8 + i]);
    const float thr = rm - WINDOW;

    const float4* row4 = (const float4*)(scores + (size_t)n * M_D);
    const int start = s * 1563;
    int end = start + 1563; if (end > M_D / 4) end = M_D / 4;

    for (int i = start + tid; i < end; i += 256) {
        float4 v = row4[i];
        if (v.x >= thr || v.y >= thr || v.z >= thr || v.w >= thr) {
            float e[4] = {v.x, v.y, v.z, v.w};
#pragma unroll
            for (int j = 0; j < 4; ++j) {
                if (e[j] >= thr) {
                    int p = atomicAdd(&ccnt[n], 1);   // rare (~1-5/row)
                    if (p < CAND_CAP) cidx[n * CAND_CAP + p] = i * 4 + j;
                }
            }
        }
    }
}

// ---------------------------------------------------------------------------
// K3: per row: exact fp32 logits for candidates (wave-parallel), softmax,
//     sparse weighted sum
// ---------------------------------------------------------------------------
__global__ __launch_bounds__(256) void finalize_rows(const float* __restrict__ x,
                                                     const float* __restrict__ dset,
                                                     const int* __restrict__ cidx,
                                                     const int* __restrict__ ccnt,
                                                     float* __restrict__ out) {
    const int n = blockIdx.x;
    const int tid = threadIdx.x;
    const int w = tid >> 6, l = tid & 63;
    int cnt = ccnt[n]; if (cnt > CAND_CAP) cnt = CAND_CAP;

    __shared__ float L[CAND_CAP];
    const float4* xr4 = (const float4*)(x + (size_t)n * K_D);

    // wave w handles candidates w, w+4, ... (no per-candidate barriers)
    for (int c = w; c < cnt; c += 4) {
        const float4* dr4 = (const float4*)(dset + (size_t)cidx[n * CAND_CAP + c] * K_D);
        float p = 0.f;
        for (int j = l; j < K_D / 4; j += 64) {      // 12 iters
            float4 a = xr4[j], b = dr4[j];
            p += a.x * b.x + a.y * b.y + a.z * b.z + a.w * b.w;
        }
#pragma unroll
        for (int off = 32; off > 0; off >>= 1) p += __shfl_down(p, off);
        if (l == 0) L[c] = 4.0f * p;                 // logit = dot / noise_var
    }
    __syncthreads();

    // softmax over candidates (cnt tiny; L becomes weights)
    if (tid == 0) {
        float mx = -3.0e38f;
        for (int c = 0; c < cnt; ++c) mx = fmaxf(mx, L[c]);
        float s = 0.f;
        for (int c = 0; c < cnt; ++c) { float e = expf(L[c] - mx); L[c] = e; s += e; }
        float inv = 1.0f / s;
        for (int c = 0; c < cnt; ++c) L[c] *= inv;
    }
    __syncthreads();

    // out[n][:] = sum_c w_c * dataset[cand_c][:]
    float4* out4 = (float4*)(out + (size_t)n * K_D);
    for (int j = tid; j < K_D / 4; j += 256) {
        float4 o = {0.f, 0.f, 0.f, 0.f};
        for (int c = 0; c < cnt; ++c) {
            float wc = L[c];
            float4 d = *(const float4*)(dset + (size_t)cidx[n * CAND_CAP + c] * K_D + j * 4);
            o.x += wc * d.x; o.y += wc * d.y; o.z += wc * d.z; o.w += wc * d.w;
        }
        out4[j] = o;
    }
}

// ---------------------------------------------------------------------------
extern "C" void kernel_launch(void* const* d_in, const int* in_sizes, int n_in,
                              void* d_out, int out_size, void* d_ws, size_t ws_size,
                              hipStream_t stream) {
    const float* x = (const float*)d_in[0];      // [256,3,32,32]
    const float* dset = (const float*)d_in[1];   // [50000,3,32,32]
    float* out = (float*)d_out;

    // workspace layout (all offsets 256B-aligned):
    //   xb      : 256*3072 bf16      = 1,572,864 B
    //   scores  : 256*50000 fp32     = 51,200,000 B
    //   pmax    : 256*8 fp32         = 8,192 B
    //   cidx    : 256*128 int        = 131,072 B
    //   ccnt    : 256 int            = 1,024 B
    char* ws = (char*)d_ws;
    short* xb = (short*)ws;
    float* scores = (float*)(ws + 1572864);
    float* pmax   = (float*)(ws + 1572864 + 51200000);
    int* cidx     = (int*)(ws + 1572864 + 51200000 + 8192);
    int* ccnt     = (int*)(ws + 1572864 + 51200000 + 8192 + 131072);

    cvt_x_kernel<<<768, 256, 0, stream>>>(x, xb);
    gemm_scores<<<(M_D + MT - 1) / MT, 256, 0, stream>>>(xb, dset, scores);
    rowmax_kernel<<<N_Q * SPLIT, 256, 0, stream>>>(scores, pmax, ccnt);
    collect_kernel<<<N_Q * SPLIT, 256, 0, stream>>>(scores, pmax, cidx, ccnt);
    finalize_rows<<<N_Q, 256, 0, stream>>>(x, dset, cidx, ccnt, out);
}